// Round 16
// baseline (265.178 us; speedup 1.0000x reference)
//
#include <hip/hip_runtime.h>
#include <hip/hip_bf16.h>

// NeRF coarse renderer — wave-group-specialized 2-ray pipeline.
// Waves 0-3 (G0) process ray r0; waves 4-7 (G1) process ray r1, schedule
// shifted one region so G0's MFMA phases overlap G1's VALU phases on every
// SIMD (waves s, s+4 share SIMD s => one MFMA-wave + one VALU-wave each).
//   R1: G0 ph1            | R2: G0 ph2 (MFMA) ∥ G1 ph1 (VALU)
//   R3: G0 ph3+4 (VALU)   ∥ G1 ph2 (MFMA)
//   R4: G0 ph5            ∥ G1 ph3+4      | R5: G1 ph5
// Layer 2 bf16 MFMA: rows 0-47 1-term Ah*Bh; rows 48-63 3-term (sigma STEP).
// GEMM split 4 waves/ray: wave gw owns ntg = gw*4..gw*4+3 (acc[4][4]).
// Layer 3 MFMA, K=64/wave (2 half-frags, k-map g(hi,e)=(e&1)*16+hi*4+(e>>1)).
// sigma_63 f32-exact via comb[gw][63][3] overwrite (same-wave DS order).
// LDS: A0,A1 32K (ah -> h2f) + L0,L1 8K (al3 -> comb) = 81920 B, 2 blocks/CU.

constexpr int H  = 256;
constexpr int KS = 64;

typedef __attribute__((ext_vector_type(8))) short short8;
typedef __attribute__((ext_vector_type(4))) float f32x4;

__device__ __forceinline__ f32x4 mfma16(short8 a, short8 b, f32x4 c) {
    return __builtin_amdgcn_mfma_f32_16x16x32_bf16(a, b, c, 0, 0, 0);
}
__device__ __forceinline__ void split_bf16(float x, short& hi, short& lo) {
    __hip_bfloat16 h = __float2bfloat16(x);
    float hf = __bfloat162float(h);
    __hip_bfloat16 l = __float2bfloat16(x - hf);
    union { __hip_bfloat16 b; short s; } c1, c2;
    c1.b = h; c2.b = l;
    hi = c1.s; lo = c2.s;
}
__device__ __forceinline__ unsigned short f2bf(float x) {
    union { __hip_bfloat16 b; unsigned short s; } c;
    c.b = __float2bfloat16(x);
    return c.s;
}
__device__ __forceinline__ float bf2f(unsigned short s) {
    union { unsigned int u; float f; } c;
    c.u = ((unsigned int)s) << 16;
    return c.f;
}
__device__ __forceinline__ unsigned int pack2bf(float a, float b) {
    return (unsigned int)f2bf(a) | ((unsigned int)f2bf(b) << 16);
}

__global__ void pack_w2_kernel(const float* __restrict__ W2,
                               unsigned short* __restrict__ hi,
                               unsigned short* __restrict__ lo)
{
    const int i  = blockIdx.x * 256 + threadIdx.x;
    const int e  = i & 7;
    const int l  = (i >> 3) & 63;
    const int nt = (i >> 9) & 15;
    const int ks = i >> 13;
    const int k  = ks * 32 + (l >> 4) * 8 + e;
    const int n  = nt * 16 + (l & 15);
    short h, lw;
    split_bf16(W2[k * H + n], h, lw);
    hi[i] = (unsigned short)h;
    lo[i] = (unsigned short)lw;
}

struct SM {
    unsigned short A0[8 * 4 * 64 * 8];   // 32 KiB: r0 ah -> h2f(r0)
    unsigned short A1[8 * 4 * 64 * 8];   // 32 KiB: r1 ah -> h2f(r1)
    unsigned short L0[8 * 64 * 8];       //  8 KiB: r0 al3 -> comb0 f32[4][64][4]
    unsigned short L1[8 * 64 * 8];       //  8 KiB: r1 al3 -> comb1
};                                       // 81920 B

// ----------------- phase macros (group-relative; no lambdas) -----------------
#define PH1(Abuf, Lbuf)                                                          \
do {                                                                             \
    _Pragma("unroll")                                                            \
    for (int ii = 0; ii < 2; ++ii) {                                             \
        const int ksi   = gw + 4 * ii;                                           \
        const int kbase = ksi * 32 + (lane >> 4) * 8;                            \
        float w1r[3][8], b1r[8];                                                 \
        _Pragma("unroll")                                                        \
        for (int c = 0; c < 3; ++c) {                                            \
            const f32x4 a_ = *(const f32x4*)&W1[c * H + kbase];                  \
            const f32x4 b_ = *(const f32x4*)&W1[c * H + kbase + 4];              \
            _Pragma("unroll")                                                    \
            for (int e = 0; e < 4; ++e) { w1r[c][e] = a_[e]; w1r[c][e+4] = b_[e]; } \
        }                                                                        \
        {                                                                        \
            const f32x4 a_ = *(const f32x4*)&b1[kbase];                          \
            const f32x4 b_ = *(const f32x4*)&b1[kbase + 4];                      \
            _Pragma("unroll")                                                    \
            for (int e = 0; e < 4; ++e) { b1r[e] = a_[e]; b1r[e+4] = b_[e]; }    \
        }                                                                        \
        const int prow = lane & 15;                                              \
        _Pragma("unroll")                                                        \
        for (int mt = 0; mt < 4; ++mt) {                                         \
            const int srow = mt * 16 + prow;                                     \
            const float uu = (float)srow * (1.0f / 63.0f);                       \
            const float z  = nr * (1.0f - uu) + fa * uu;                         \
            const float px = cx + z * dx, py = cy + z * dy, pz = cz + z * dz;    \
            float xs[8];                                                         \
            _Pragma("unroll")                                                    \
            for (int e = 0; e < 8; ++e) {                                        \
                float x = fmaf(px, w1r[0][e],                                    \
                          fmaf(py, w1r[1][e],                                    \
                          fmaf(pz, w1r[2][e], b1r[e])));                         \
                xs[e] = fmaxf(x, 0.0f);                                          \
            }                                                                    \
            unsigned int hw[4];                                                  \
            _Pragma("unroll")                                                    \
            for (int p2 = 0; p2 < 4; ++p2) hw[p2] = pack2bf(xs[p2*2], xs[p2*2+1]); \
            unsigned int* dst = (unsigned int*)&(Abuf)[((ksi*4+mt)*64+lane)*8];  \
            dst[0] = hw[0]; dst[1] = hw[1]; dst[2] = hw[2]; dst[3] = hw[3];      \
            if (mt == 3) {                                                       \
                unsigned int lw[4];                                              \
                _Pragma("unroll")                                                \
                for (int p2 = 0; p2 < 4; ++p2) {                                 \
                    const float l0 = xs[p2*2]   - bf2f((unsigned short)(hw[p2] & 0xffffu)); \
                    const float l1 = xs[p2*2+1] - bf2f((unsigned short)(hw[p2] >> 16));     \
                    lw[p2] = pack2bf(l0, l1);                                    \
                }                                                                \
                unsigned int* dl = (unsigned int*)&(Lbuf)[(ksi*64+lane)*8];      \
                dl[0] = lw[0]; dl[1] = lw[1]; dl[2] = lw[2]; dl[3] = lw[3];      \
            }                                                                    \
        }                                                                        \
    }                                                                            \
} while (0)

#define ACCINIT()                                                                \
do {                                                                             \
    _Pragma("unroll")                                                            \
    for (int mt = 0; mt < 4; ++mt) {                                             \
        acc[mt][0] = (f32x4){b2c0_, b2c0_, b2c0_, b2c0_};                        \
        acc[mt][1] = (f32x4){b2c1_, b2c1_, b2c1_, b2c1_};                        \
        acc[mt][2] = (f32x4){b2c2_, b2c2_, b2c2_, b2c2_};                        \
        acc[mt][3] = (f32x4){b2c3_, b2c3_, b2c3_, b2c3_};                        \
    }                                                                            \
} while (0)

#define PH2(Abuf, Lbuf)                                                          \
do {                                                                             \
    const short8* Bh = (const short8*)w2h;                                       \
    const short8* Bl = (const short8*)w2l;                                       \
    const short8* Ah = (const short8*)(Abuf);                                    \
    const short8* Al = (const short8*)(Lbuf);                                    \
    __builtin_amdgcn_s_setprio(1);                                               \
    _Pragma("unroll 1")                                                          \
    for (int ks = 0; ks < 8; ++ks) {                                             \
        short8 bh[4];                                                            \
        _Pragma("unroll")                                                        \
        for (int v = 0; v < 4; ++v)                                              \
            bh[v] = Bh[(ks * 16 + gw * 4 + v) * 64 + lane];                      \
        _Pragma("unroll")                                                        \
        for (int mt = 0; mt < 4; ++mt) {                                         \
            const short8 ah = Ah[(ks * 4 + mt) * 64 + lane];                     \
            _Pragma("unroll")                                                    \
            for (int v = 0; v < 4; ++v)                                          \
                acc[mt][v] = mfma16(ah, bh[v], acc[mt][v]);                      \
            if (mt == 3) {                                                       \
                const short8 al = Al[ks * 64 + lane];                            \
                _Pragma("unroll")                                                \
                for (int v = 0; v < 4; ++v) {                                    \
                    const short8 bl = Bl[(ks * 16 + gw * 4 + v) * 64 + lane];    \
                    acc[3][v] = mfma16(ah, bl, acc[3][v]);                       \
                    acc[3][v] = mfma16(al, bh[v], acc[3][v]);                    \
                }                                                                \
            }                                                                    \
        }                                                                        \
    }                                                                            \
    __builtin_amdgcn_s_setprio(0);                                               \
} while (0)

// h2 -> bf16 layer-3 A-frags. Wave gw owns cols 64gw..64gw+63 (2 half-slices of
// K=32, k-map g(hi,e)=(e&1)*16+hi*4+(e>>1)); pair (j0,j0+16) packs into one u32.
#define PH3(H2F)                                                                 \
do {                                                                             \
    const int rlow = (lane >> 4) * 4;                                            \
    const int hi2  = j0 >> 2;                                                    \
    const int e0   = (j0 & 3) * 2;                                               \
    _Pragma("unroll")                                                            \
    for (int mt = 0; mt < 4; ++mt) {                                             \
        _Pragma("unroll")                                                        \
        for (int q = 0; q < 4; ++q) {                                            \
            const float a0 = fmaxf(acc[mt][0][q], 0.0f);                         \
            const float a1 = fmaxf(acc[mt][1][q], 0.0f);                         \
            const float a2 = fmaxf(acc[mt][2][q], 0.0f);                         \
            const float a3 = fmaxf(acc[mt][3][q], 0.0f);                         \
            const int l2 = (hi2 << 4) | (rlow + q);                              \
            *(unsigned int*)&(H2F)[(((gw*2+0)*4+mt)*64 + l2)*8 + e0] = pack2bf(a0, a1); \
            *(unsigned int*)&(H2F)[(((gw*2+1)*4+mt)*64 + l2)*8 + e0] = pack2bf(a2, a3); \
            if (mt == 3 && q == 3) { r63_0 = a0; r63_1 = a1; r63_2 = a2; r63_3 = a3; } \
        }                                                                        \
    }                                                                            \
} while (0)

#define PH4(H2F, COMB)                                                           \
do {                                                                             \
    const int hi = lane >> 4;                                                    \
    short8 bw0, bw1;                                                             \
    _Pragma("unroll")                                                            \
    for (int e = 0; e < 8; ++e) {                                                \
        const int kl = (e & 1) * 16 + hi * 4 + (e >> 1);                         \
        const int k0 = 64 * gw + kl;                                             \
        const int k1 = k0 + 32;                                                  \
        bw0[e] = (short)f2bf((j0 < 4) ? W3[k0 * 4 + j0] : 0.0f);                 \
        bw1[e] = (short)f2bf((j0 < 4) ? W3[k1 * 4 + j0] : 0.0f);                 \
    }                                                                            \
    const short8* Ah2 = (const short8*)(H2F);                                    \
    _Pragma("unroll")                                                            \
    for (int mt = 0; mt < 4; ++mt) {                                             \
        const short8 a0_ = Ah2[((gw*2+0)*4 + mt)*64 + lane];                     \
        const short8 a1_ = Ah2[((gw*2+1)*4 + mt)*64 + lane];                     \
        f32x4 d = (f32x4){0.f,0.f,0.f,0.f};                                      \
        d = mfma16(a0_, bw0, d);                                                 \
        d = mfma16(a1_, bw1, d);                                                 \
        if (j0 < 4) {                                                            \
            _Pragma("unroll")                                                    \
            for (int q = 0; q < 4; ++q)                                          \
                (COMB)[(gw * 64 + mt * 16 + hi * 4 + q) * 4 + j0] = d[q];        \
        }                                                                        \
    }                                                                            \
    if (lastGrp) {                                                               \
        float p = fmaf(r63_0, W3[(64*gw+j0)*4+3],                                \
                  fmaf(r63_1, W3[(64*gw+16+j0)*4+3],                             \
                  fmaf(r63_2, W3[(64*gw+32+j0)*4+3],                             \
                       r63_3 * W3[(64*gw+48+j0)*4+3])));                         \
        _Pragma("unroll")                                                        \
        for (int off = 1; off < 16; off <<= 1) p += __shfl_xor(p, off, 64);      \
        if (j0 == 0) (COMB)[(gw * 64 + 63) * 4 + 3] = p;                         \
    }                                                                            \
} while (0)

#define PH5(COMB, r_)                                                            \
do {                                                                             \
    const int s = lane;                                                          \
    f32x4 oo = (f32x4){0.f,0.f,0.f,0.f};                                         \
    _Pragma("unroll")                                                            \
    for (int q = 0; q < 4; ++q) {                                                \
        const f32x4 c_ = *(const f32x4*)&(COMB)[(q * 64 + s) * 4];               \
        oo[0] += c_[0]; oo[1] += c_[1]; oo[2] += c_[2]; oo[3] += c_[3];          \
    }                                                                            \
    const float o0 = oo[0] + b3[0];                                              \
    const float o1 = oo[1] + b3[1];                                              \
    const float o2 = oo[2] + b3[2];                                              \
    const float sigma = oo[3] + b3[3];                                           \
    const float uu = (float)s * (1.0f / 63.0f);                                  \
    const float z  = nr * (1.0f - uu) + fa * uu;                                 \
    const float u2 = (float)(s + 1) * (1.0f / 63.0f);                            \
    const float z2 = nr * (1.0f - u2) + fa * u2;                                 \
    const float delta = (s == 63) ? 1e10f : (z2 - z);                            \
    const float alpha = 1.0f - __expf(-delta * fmaxf(sigma, 0.0f));              \
    float P = 1.0f - alpha + 1e-8f;                                              \
    _Pragma("unroll")                                                            \
    for (int off = 1; off < 64; off <<= 1) {                                     \
        const float v_ = __shfl_up(P, off, 64);                                  \
        if (s >= off) P *= v_;                                                   \
    }                                                                            \
    float T = __shfl_up(P, 1, 64);                                               \
    if (s == 0) T = 1.0f;                                                        \
    const float w_ = alpha * T;                                                  \
    out[(size_t)B * 4 + (size_t)(r_) * 64 + s] = w_;                             \
    float ws = w_, dep = w_ * z, q0 = w_ * o0, q1 = w_ * o1, q2 = w_ * o2;       \
    _Pragma("unroll")                                                            \
    for (int off = 32; off > 0; off >>= 1) {                                     \
        ws  += __shfl_xor(ws,  off, 64);                                         \
        dep += __shfl_xor(dep, off, 64);                                         \
        q0  += __shfl_xor(q0,  off, 64);                                         \
        q1  += __shfl_xor(q1,  off, 64);                                         \
        q2  += __shfl_xor(q2,  off, 64);                                         \
    }                                                                            \
    const float sl = __shfl(sigma, 63, 64);                                      \
    if (s == 0) {                                                                \
        out[(size_t)(r_) * 3 + 0] = q0 + 1.0f - ws;                              \
        out[(size_t)(r_) * 3 + 1] = q1 + 1.0f - ws;                              \
        out[(size_t)(r_) * 3 + 2] = q2 + 1.0f - ws;                              \
        out[(size_t)B * 3 + (r_)] = dep;                                         \
        out[(size_t)B * 68 + (r_)] = sl;                                         \
    }                                                                            \
} while (0)

__launch_bounds__(512, 4)
__global__ void nerf_mfma_kernel(
    const float* __restrict__ g_near, const float* __restrict__ g_far,
    const float* __restrict__ g_center, const float* __restrict__ g_dir,
    const float* __restrict__ W1, const float* __restrict__ b1,
    const float* __restrict__ b2,
    const float* __restrict__ W3, const float* __restrict__ b3,
    const unsigned short* __restrict__ w2h, const unsigned short* __restrict__ w2l,
    float* __restrict__ out, int B)
{
    __shared__ __align__(16) SM sm;

    const int t    = threadIdx.x;
    const int lane = t & 63;
    const int wv   = __builtin_amdgcn_readfirstlane(t >> 6);   // 0..7
    const int grp  = wv >> 2;                                  // 0: ray0, 1: ray1
    const int gw   = wv & 3;                                   // wave-in-group
    const int r0   = blockIdx.x * 2;
    const int r1g  = r0 + 1;
    const int ray  = grp ? min(r1g, B - 1) : r0;
    const int rOut = grp ? r1g : r0;

    // ---- this group's ray params ----
    const float nr = g_near[ray], fa = g_far[ray];
    const float cx = g_center[ray*3+0], cy = g_center[ray*3+1], cz = g_center[ray*3+2];
    const float dx = g_dir[ray*3+0],    dy = g_dir[ray*3+1],    dz = g_dir[ray*3+2];

    // ---- per-thread constants ----
    const int  j0 = lane & 15;
    const bool lastGrp = ((lane >> 4) == 3);
    const float b2c0_ = b2[64*gw + j0];
    const float b2c1_ = b2[64*gw + 16 + j0];
    const float b2c2_ = b2[64*gw + 32 + j0];
    const float b2c3_ = b2[64*gw + 48 + j0];

    unsigned short* Abuf = grp ? sm.A1 : sm.A0;
    unsigned short* Lbuf = grp ? sm.L1 : sm.L0;
    float* COMB = (float*)Lbuf;

    f32x4 acc[4][4];
    float r63_0 = 0.f, r63_1 = 0.f, r63_2 = 0.f, r63_3 = 0.f;

    // ================= phase-shifted pipeline =================
    // R1: G0 ph1
    if (!grp) PH1(Abuf, Lbuf);
    __syncthreads();

    // R2: G0 ph2 (MFMA)  ∥  G1 ph1 (VALU)
    if (!grp) { ACCINIT(); PH2(Abuf, Lbuf); }
    else      { PH1(Abuf, Lbuf); }
    __syncthreads();

    // R3: G0 ph3+ph4 (VALU+小MFMA)  ∥  G1 ph2 (MFMA)
    if (!grp) { PH3(Abuf); PH4(Abuf, COMB); }
    else      { ACCINIT(); PH2(Abuf, Lbuf); }
    __syncthreads();

    // R4: G0 ph5  ∥  G1 ph3+ph4
    if (!grp) { if (gw == 0) PH5(COMB, r0); }
    else      { PH3(Abuf); PH4(Abuf, COMB); }
    __syncthreads();

    // R5: G1 ph5
    if (grp && gw == 0 && rOut < B) PH5(COMB, rOut);
}

extern "C" void kernel_launch(void* const* d_in, const int* in_sizes, int n_in,
                              void* d_out, int out_size, void* d_ws, size_t ws_size,
                              hipStream_t stream)
{
    const int B = in_sizes[0];
    if (ws_size < (size_t)(2 * 65536 * sizeof(unsigned short))) return;

    unsigned short* w2h = (unsigned short*)d_ws;
    unsigned short* w2l = w2h + 65536;

    pack_w2_kernel<<<256, 256, 0, stream>>>((const float*)d_in[6], w2h, w2l);

    const int grid = (B + 1) / 2;
    nerf_mfma_kernel<<<grid, 512, 0, stream>>>(
        (const float*)d_in[0], (const float*)d_in[1],
        (const float*)d_in[2], (const float*)d_in[3],
        (const float*)d_in[4], (const float*)d_in[5],
        (const float*)d_in[7],
        (const float*)d_in[8], (const float*)d_in[9],
        w2h, w2l,
        (float*)d_out, B);
}

// Round 17
// 256.045 us; speedup vs baseline: 1.0357x; 1.0357x over previous
//
#include <hip/hip_runtime.h>
#include <hip/hip_bf16.h>

// NeRF coarse renderer. Layer 2 on bf16 MFMA:
//   rows 0-47:  h2 = Ah*Bh                 (1-term, err ~sqrt2*2^-9, rgb-smooth path)
//   rows 48-63: h2 = Ah*(Bh+Bl) + Al*Bh    (3-term — sample 63 feeds the
//                                           alpha = 1-exp(-1e10*relu(sigma)) STEP)
// Layer 3 on MFMA (wave-K-split). Shared A/B k-map g(hi,e)=(e&1)*16+hi*4+(e>>1)
// => phase 3 writes (col j, col j+16) pairs as one packed u32 (HW cvt_pk).
// Phase3->phase4 h2f round-trip is WAVE-PRIVATE => no barrier (DS in-order).
// sigma_63 f32-exact: partial-dot written into comb[wv][63][3] AFTER phase-4's
// stores (same-wave DS order guarantees it wins). 4 barriers total.
// 1 ray/block, LDS 40960 B => 4 blocks/CU, launch_bounds(512,8).
//
// NEW (r17): one-time start stagger for the first resident batch
// (blockIdx < 1024): co-resident blocks otherwise run phase-locked (identical
// code, identical rate) so MFMA and VALU phases never overlap across blocks —
// r13 counters show MfmaUtil+VALUBusy ~= 100% (serial sum). Sleeping
// q*~7us (q in 0..3, distinct for co-resident blocks under either consecutive
// or stride-256 placement) breaks the symmetry; later blocks inherit the
// stagger from staggered completions.
//
// d_in: 0 near(B,1) 1 far(B,1) 2 center(B,3) 3 dir(B,3)
//       4 W1(3,256) 5 b1(256) 6 W2(256,256) 7 b2(256) 8 W3(256,4) 9 b3(4)
// d_out: [rgb (B,3) | depth (B) | weights (B,64) | sigmas_last (B)] f32
// d_ws: W2 repacked as MFMA B-fragments, bf16 hi[64K] + lo[64K] (256 KiB).

constexpr int H  = 256;
constexpr int KS = 64;     // samples per ray = M rows per block

typedef __attribute__((ext_vector_type(8))) short short8;           // 8 bf16
typedef __attribute__((ext_vector_type(4))) float f32x4;            // C/D frag

__device__ __forceinline__ f32x4 mfma16(short8 a, short8 b, f32x4 c) {
    return __builtin_amdgcn_mfma_f32_16x16x32_bf16(a, b, c, 0, 0, 0);
}
__device__ __forceinline__ void split_bf16(float x, short& hi, short& lo) {
    __hip_bfloat16 h = __float2bfloat16(x);
    float hf = __bfloat162float(h);
    __hip_bfloat16 l = __float2bfloat16(x - hf);
    union { __hip_bfloat16 b; short s; } c1, c2;
    c1.b = h; c2.b = l;
    hi = c1.s; lo = c2.s;
}
// HW RNE casts (r12 lesson: int-trick RNE is SLOWER than the HW convert)
__device__ __forceinline__ unsigned short f2bf(float x) {
    union { __hip_bfloat16 b; unsigned short s; } c;
    c.b = __float2bfloat16(x);
    return c.s;
}
__device__ __forceinline__ float bf2f(unsigned short s) {
    union { unsigned int u; float f; } c;
    c.u = ((unsigned int)s) << 16;
    return c.f;
}
__device__ __forceinline__ unsigned int pack2bf(float a, float b) {
    return (unsigned int)f2bf(a) | ((unsigned int)f2bf(b) << 16);
}

// ---- pre-pass: pack W2 (f32 row-major [k][n]) into frag-ordered bf16 hi/lo.
// Element i = ((ks*16 + ntg)*64 + lane)*8 + e  maps to
//   k = ks*32 + (lane>>4)*8 + e,  n = ntg*16 + (lane&15).
__global__ void pack_w2_kernel(const float* __restrict__ W2,
                               unsigned short* __restrict__ hi,
                               unsigned short* __restrict__ lo)
{
    const int i  = blockIdx.x * 256 + threadIdx.x;   // 0..65535
    const int e  = i & 7;
    const int l  = (i >> 3) & 63;
    const int nt = (i >> 9) & 15;
    const int ks = i >> 13;
    const int k  = ks * 32 + (l >> 4) * 8 + e;
    const int n  = nt * 16 + (l & 15);
    short h, lw;
    split_bf16(W2[k * H + n], h, lw);
    hi[i] = (unsigned short)h;
    lo[i] = (unsigned short)lw;
}

// LDS, lifetime-aliased, 40960 B total => 4 blocks/CU:
//   big (32 KiB): ah A-frags (ph1->ph2)  ALIASES  h2f layer-3 A-frags (ph3->ph4)
//   r2  ( 8 KiB): al3 lo A-frags mt3 (ph1->ph2)  ALIASES  comb[8][64][4] (ph3->ph5)
struct R2a { unsigned short al3[8 * 64 * 8]; };              // 8 KiB
struct R2b { float comb[8][KS][4]; };                        // 8 KiB
union  R2  { R2a a; R2b b; };
struct SM {
    union { unsigned short ah[8 * 4 * 64 * 8];
            unsigned short h2f[8 * 4 * 64 * 8]; } big;       // 32 KiB
    R2 r2;                                                   //  8 KiB
};

__launch_bounds__(512, 8)
__global__ void nerf_mfma_kernel(
    const float* __restrict__ g_near, const float* __restrict__ g_far,
    const float* __restrict__ g_center, const float* __restrict__ g_dir,
    const float* __restrict__ W1, const float* __restrict__ b1,
    const float* __restrict__ b2,
    const float* __restrict__ W3, const float* __restrict__ b3,
    const unsigned short* __restrict__ w2h, const unsigned short* __restrict__ w2l,
    float* __restrict__ out, int B)
{
    __shared__ __align__(16) SM sm;

    const int t    = threadIdx.x;
    const int lane = t & 63;
    const int wv   = __builtin_amdgcn_readfirstlane(t >> 6);   // 0..7
    const int r    = blockIdx.x;                               // ray id

    // ---- one-time start stagger (first resident batch only) ----
    // q distinct among co-resident blocks whether placement groups consecutive
    // ids or stride-256 ids; ~3.4us per unit pair, q*2 units => 0/6.8/13.6/20.4us.
    if (blockIdx.x < 1024) {
        const int q = ((blockIdx.x >> 8) ^ blockIdx.x) & 3;
        for (int i = 0; i < q * 2; ++i) __builtin_amdgcn_s_sleep(127);
    }

    // ---- ray params (block-uniform scalar loads) ----
    const float nr = g_near[r], fa = g_far[r];
    const float cx = g_center[r*3+0], cy = g_center[r*3+1], cz = g_center[r*3+2];
    const float dx = g_dir[r*3+0],    dy = g_dir[r*3+1],    dz = g_dir[r*3+2];

    // ---- phase 1: layer 1 (f32, points recomputed in-register);
    //      h1 -> bf16 A-frags (hi; +lo for mt==3) ----
    {
        const int kbase = wv * 32 + (lane >> 4) * 8;   // 8 consecutive k
        float w1r[3][8], b1r[8];
        #pragma unroll
        for (int c = 0; c < 3; ++c) {
            const f32x4 a = *(const f32x4*)&W1[c * H + kbase];
            const f32x4 b = *(const f32x4*)&W1[c * H + kbase + 4];
            #pragma unroll
            for (int e = 0; e < 4; ++e) { w1r[c][e] = a[e]; w1r[c][e+4] = b[e]; }
        }
        {
            const f32x4 a = *(const f32x4*)&b1[kbase];
            const f32x4 b = *(const f32x4*)&b1[kbase + 4];
            #pragma unroll
            for (int e = 0; e < 4; ++e) { b1r[e] = a[e]; b1r[e+4] = b[e]; }
        }
        const int prow = lane & 15;
        #pragma unroll
        for (int mt = 0; mt < 4; ++mt) {
            const int srow = mt * 16 + prow;
            const float uu = (float)srow * (1.0f / 63.0f);
            const float z  = nr * (1.0f - uu) + fa * uu;
            const float px = cx + z * dx, py = cy + z * dy, pz = cz + z * dz;
            float xs[8];
            #pragma unroll
            for (int e = 0; e < 8; ++e) {
                float x = fmaf(px, w1r[0][e],
                          fmaf(py, w1r[1][e],
                          fmaf(pz, w1r[2][e], b1r[e])));
                xs[e] = fmaxf(x, 0.0f);
            }
            unsigned int hw[4];
            #pragma unroll
            for (int p2 = 0; p2 < 4; ++p2) hw[p2] = pack2bf(xs[p2*2], xs[p2*2+1]);
            *(unsigned int*)&sm.big.ah[((wv*4+mt)*64+lane)*8 + 0] = hw[0];
            *(unsigned int*)&sm.big.ah[((wv*4+mt)*64+lane)*8 + 2] = hw[1];
            *(unsigned int*)&sm.big.ah[((wv*4+mt)*64+lane)*8 + 4] = hw[2];
            *(unsigned int*)&sm.big.ah[((wv*4+mt)*64+lane)*8 + 6] = hw[3];
            if (mt == 3) {
                unsigned int lw[4];
                #pragma unroll
                for (int p2 = 0; p2 < 4; ++p2) {
                    const float l0 = xs[p2*2]   - bf2f((unsigned short)(hw[p2] & 0xffffu));
                    const float l1 = xs[p2*2+1] - bf2f((unsigned short)(hw[p2] >> 16));
                    lw[p2] = pack2bf(l0, l1);
                }
                *(unsigned int*)&sm.r2.a.al3[(wv*64+lane)*8 + 0] = lw[0];
                *(unsigned int*)&sm.r2.a.al3[(wv*64+lane)*8 + 2] = lw[1];
                *(unsigned int*)&sm.r2.a.al3[(wv*64+lane)*8 + 4] = lw[2];
                *(unsigned int*)&sm.r2.a.al3[(wv*64+lane)*8 + 6] = lw[3];
            }
        }
    }
    __syncthreads();

    // ---- phase 2: layer 2 GEMM via MFMA (1-term; mt3 = 3-term) ----
    f32x4 acc[4][2];
    #pragma unroll
    for (int mt = 0; mt < 4; ++mt) {
        acc[mt][0] = (f32x4){0.f,0.f,0.f,0.f};
        acc[mt][1] = (f32x4){0.f,0.f,0.f,0.f};
    }
    {
        const int ntg0 = wv * 2, ntg1 = ntg0 + 1;
        const short8* Bh = (const short8*)w2h;
        const short8* Bl = (const short8*)w2l;
        const short8* Ah = (const short8*)sm.big.ah;
        const short8* Al = (const short8*)sm.r2.a.al3;
        __builtin_amdgcn_s_setprio(1);
        #pragma unroll
        for (int ks = 0; ks < 8; ++ks) {
            const short8 b0h  = Bh[(ks * 16 + ntg0) * 64 + lane];
            const short8 b1h_ = Bh[(ks * 16 + ntg1) * 64 + lane];
            #pragma unroll
            for (int mt = 0; mt < 4; ++mt) {
                const short8 ah = Ah[(ks * 4 + mt) * 64 + lane];
                f32x4 c0 = acc[mt][0], c1 = acc[mt][1];
                c0 = mfma16(ah, b0h, c0);
                c1 = mfma16(ah, b1h_, c1);
                if (mt == 3) {               // sigma-critical rows: full 3-term
                    const short8 b0l = Bl[(ks * 16 + ntg0) * 64 + lane];
                    const short8 b1l = Bl[(ks * 16 + ntg1) * 64 + lane];
                    const short8 al  = Al[ks * 64 + lane];
                    c0 = mfma16(ah, b0l, c0);
                    c0 = mfma16(al, b0h, c0);
                    c1 = mfma16(ah, b1l, c1);
                    c1 = mfma16(al, b1h_, c1);
                }
                acc[mt][0] = c0; acc[mt][1] = c1;
            }
        }
        __builtin_amdgcn_s_setprio(0);
    }
    __syncthreads();   // ah/al3 dead; big->h2f, r2->comb reuse is now safe

    // ---- phase 3: +b2, ReLU; h2 -> A-frag order, k-map g(hi,e)=(e&1)*16+hi*4+(e>>1)
    //      (col pair (j0, j0+16) packs into one u32). NO barrier after: the h2f
    //      region written here is wave-private and re-read only by this wave. ----
    const int  j0 = lane & 15;
    const int  c0 = wv * 32 + j0;
    const int  c1 = c0 + 16;
    const bool lastGrp = ((lane >> 4) == 3);
    float r63a = 0.f, r63b = 0.f;      // f32 h2[63][c0], h2[63][c1] (lastGrp lanes)
    {
        const float b2c0 = b2[c0], b2c1 = b2[c1];
        const int rlow = (lane >> 4) * 4;
        const int hi2  = j0 >> 2;
        const int e0   = (j0 & 3) * 2;
        #pragma unroll
        for (int mt = 0; mt < 4; ++mt) {
            const f32x4 v0 = acc[mt][0], v1 = acc[mt][1];
            #pragma unroll
            for (int q = 0; q < 4; ++q) {
                const float a0 = fmaxf(v0[q] + b2c0, 0.0f);
                const float a1 = fmaxf(v1[q] + b2c1, 0.0f);
                const int l2 = (hi2 << 4) | (rlow + q);
                *(unsigned int*)&sm.big.h2f[((wv*4+mt)*64 + l2)*8 + e0] = pack2bf(a0, a1);
                if (mt == 3 && q == 3) { r63a = a0; r63b = a1; }
            }
        }
    }
    // (no __syncthreads here)

    // ---- phase 4: layer 3 via MFMA, K-split across waves -> comb[wv];
    //      then same-wave DS-ordered overwrite of comb[wv][63][3] with f32 sigma63
    {
        // W3 B-frag with the SAME k-map: k = wv*32 + (e&1)*16 + hi*4 + (e>>1)
        const int n  = lane & 15;
        const int hi = lane >> 4;
        short8 bw3;
        #pragma unroll
        for (int e = 0; e < 8; ++e) {
            const int k = wv * 32 + (e & 1) * 16 + hi * 4 + (e >> 1);
            const float v = (n < 4) ? W3[k * 4 + n] : 0.0f;
            bw3[e] = (short)f2bf(v);
        }
        const short8* Ah2 = (const short8*)sm.big.h2f;
        #pragma unroll
        for (int mt = 0; mt < 4; ++mt) {
            const short8 a = Ah2[(wv * 4 + mt) * 64 + lane];
            f32x4 d = (f32x4){0.f,0.f,0.f,0.f};
            d = mfma16(a, bw3, d);
            if (n < 4) {
                #pragma unroll
                for (int q = 0; q < 4; ++q)
                    sm.r2.b.comb[wv][mt * 16 + hi * 4 + q][n] = d[q];
            }
        }
        if (lastGrp) {   // lanes 48-63 hold row 63; program order => this wins
            float p = fmaf(r63a, W3[c0 * 4 + 3], r63b * W3[c1 * 4 + 3]);
            #pragma unroll
            for (int off = 1; off < 16; off <<= 1) p += __shfl_xor(p, off, 64);
            if (j0 == 0) sm.r2.b.comb[wv][63][3] = p;
        }
    }
    __syncthreads();

    // ---- phase 5: volume rendering (wave 0, lane = sample) ----
    if (t < KS) {
        const int s = t;

        f32x4 oo = (f32x4){0.f,0.f,0.f,0.f};
        #pragma unroll
        for (int q = 0; q < 8; ++q) {
            const f32x4 c = *(const f32x4*)&sm.r2.b.comb[q][s][0];
            oo[0] += c[0]; oo[1] += c[1]; oo[2] += c[2]; oo[3] += c[3];
        }
        const float o0 = oo[0] + b3[0];
        const float o1 = oo[1] + b3[1];
        const float o2 = oo[2] + b3[2];
        const float sigma = oo[3] + b3[3];   // s=63: f32-exact via comb[*][63][3]

        const float uu = (float)s * (1.0f / 63.0f);
        const float z  = nr * (1.0f - uu) + fa * uu;
        const float u2 = (float)(s + 1) * (1.0f / 63.0f);
        const float z2 = nr * (1.0f - u2) + fa * u2;
        const float delta = (s == 63) ? 1e10f : (z2 - z);
        const float alpha = 1.0f - __expf(-delta * fmaxf(sigma, 0.0f));

        // exclusive product scan of (1 - alpha + eps)
        float P = 1.0f - alpha + 1e-8f;
        #pragma unroll
        for (int off = 1; off < 64; off <<= 1) {
            const float v = __shfl_up(P, off, 64);
            if (s >= off) P *= v;
        }
        float T = __shfl_up(P, 1, 64);
        if (s == 0) T = 1.0f;
        const float w = alpha * T;

        out[(size_t)B * 4 + (size_t)r * 64 + s] = w;

        float ws = w, dep = w * z, q0 = w * o0, q1 = w * o1, q2 = w * o2;
        #pragma unroll
        for (int off = 32; off > 0; off >>= 1) {
            ws  += __shfl_xor(ws,  off, 64);
            dep += __shfl_xor(dep, off, 64);
            q0  += __shfl_xor(q0,  off, 64);
            q1  += __shfl_xor(q1,  off, 64);
            q2  += __shfl_xor(q2,  off, 64);
        }
        const float sl = __shfl(sigma, 63, 64);
        if (s == 0) {
            out[(size_t)r * 3 + 0] = q0 + 1.0f - ws;
            out[(size_t)r * 3 + 1] = q1 + 1.0f - ws;
            out[(size_t)r * 3 + 2] = q2 + 1.0f - ws;
            out[(size_t)B * 3 + r] = dep;
            out[(size_t)B * 68 + r] = sl;
        }
    }
}

extern "C" void kernel_launch(void* const* d_in, const int* in_sizes, int n_in,
                              void* d_out, int out_size, void* d_ws, size_t ws_size,
                              hipStream_t stream)
{
    const int B = in_sizes[0];
    if (ws_size < (size_t)(2 * 65536 * sizeof(unsigned short))) return;  // need 256 KiB

    unsigned short* w2h = (unsigned short*)d_ws;
    unsigned short* w2l = w2h + 65536;

    pack_w2_kernel<<<256, 256, 0, stream>>>((const float*)d_in[6], w2h, w2l);

    nerf_mfma_kernel<<<B, 512, 0, stream>>>(
        (const float*)d_in[0], (const float*)d_in[1],
        (const float*)d_in[2], (const float*)d_in[3],
        (const float*)d_in[4], (const float*)d_in[5],
        (const float*)d_in[7],
        (const float*)d_in[8], (const float*)d_in[9],
        w2h, w2l,
        (float*)d_out, B);
}

// Round 18
// 243.897 us; speedup vs baseline: 1.0873x; 1.0498x over previous
//
#include <hip/hip_runtime.h>
#include <hip/hip_bf16.h>

// NeRF coarse renderer — FINAL (r13 structure, best measured: 243.9 us).
// Layer 2 on bf16 MFMA:
//   rows 0-47:  h2 = Ah*Bh                 (1-term, err ~sqrt2*2^-9, rgb-smooth path)
//   rows 48-63: h2 = Ah*(Bh+Bl) + Al*Bh    (3-term — sample 63 feeds the
//                                           alpha = 1-exp(-1e10*relu(sigma)) STEP)
// Layer 3 on MFMA (wave-K-split). Shared A/B k-map g(hi,e)=(e&1)*16+hi*4+(e>>1)
// => phase 3 writes (col j, col j+16) pairs as one packed u32 (HW cvt_pk).
// Phase3->phase4 h2f round-trip is WAVE-PRIVATE => no barrier (DS in-order).
// sigma_63 f32-exact: partial-dot written into comb[wv][63][3] AFTER phase-4's
// stores (same-wave DS order guarantees it wins). 4 barriers total.
// 1 ray/block, LDS 40960 B => 4 blocks/CU, launch_bounds(512,8).
//
// d_in: 0 near(B,1) 1 far(B,1) 2 center(B,3) 3 dir(B,3)
//       4 W1(3,256) 5 b1(256) 6 W2(256,256) 7 b2(256) 8 W3(256,4) 9 b3(4)
// d_out: [rgb (B,3) | depth (B) | weights (B,64) | sigmas_last (B)] f32
// d_ws: W2 repacked as MFMA B-fragments, bf16 hi[64K] + lo[64K] (256 KiB).

constexpr int H  = 256;
constexpr int KS = 64;     // samples per ray = M rows per block

typedef __attribute__((ext_vector_type(8))) short short8;           // 8 bf16
typedef __attribute__((ext_vector_type(4))) float f32x4;            // C/D frag

__device__ __forceinline__ f32x4 mfma16(short8 a, short8 b, f32x4 c) {
    return __builtin_amdgcn_mfma_f32_16x16x32_bf16(a, b, c, 0, 0, 0);
}
__device__ __forceinline__ void split_bf16(float x, short& hi, short& lo) {
    __hip_bfloat16 h = __float2bfloat16(x);
    float hf = __bfloat162float(h);
    __hip_bfloat16 l = __float2bfloat16(x - hf);
    union { __hip_bfloat16 b; short s; } c1, c2;
    c1.b = h; c2.b = l;
    hi = c1.s; lo = c2.s;
}
// HW RNE casts (r12 lesson: int-trick RNE is SLOWER than the HW convert)
__device__ __forceinline__ unsigned short f2bf(float x) {
    union { __hip_bfloat16 b; unsigned short s; } c;
    c.b = __float2bfloat16(x);
    return c.s;
}
__device__ __forceinline__ float bf2f(unsigned short s) {
    union { unsigned int u; float f; } c;
    c.u = ((unsigned int)s) << 16;
    return c.f;
}
__device__ __forceinline__ unsigned int pack2bf(float a, float b) {
    return (unsigned int)f2bf(a) | ((unsigned int)f2bf(b) << 16);
}

// ---- pre-pass: pack W2 (f32 row-major [k][n]) into frag-ordered bf16 hi/lo.
// Element i = ((ks*16 + ntg)*64 + lane)*8 + e  maps to
//   k = ks*32 + (lane>>4)*8 + e,  n = ntg*16 + (lane&15).
__global__ void pack_w2_kernel(const float* __restrict__ W2,
                               unsigned short* __restrict__ hi,
                               unsigned short* __restrict__ lo)
{
    const int i  = blockIdx.x * 256 + threadIdx.x;   // 0..65535
    const int e  = i & 7;
    const int l  = (i >> 3) & 63;
    const int nt = (i >> 9) & 15;
    const int ks = i >> 13;
    const int k  = ks * 32 + (l >> 4) * 8 + e;
    const int n  = nt * 16 + (l & 15);
    short h, lw;
    split_bf16(W2[k * H + n], h, lw);
    hi[i] = (unsigned short)h;
    lo[i] = (unsigned short)lw;
}

// LDS, lifetime-aliased, 40960 B total => 4 blocks/CU:
//   big (32 KiB): ah A-frags (ph1->ph2)  ALIASES  h2f layer-3 A-frags (ph3->ph4)
//   r2  ( 8 KiB): al3 lo A-frags mt3 (ph1->ph2)  ALIASES  comb[8][64][4] (ph3->ph5)
struct R2a { unsigned short al3[8 * 64 * 8]; };              // 8 KiB
struct R2b { float comb[8][KS][4]; };                        // 8 KiB
union  R2  { R2a a; R2b b; };
struct SM {
    union { unsigned short ah[8 * 4 * 64 * 8];
            unsigned short h2f[8 * 4 * 64 * 8]; } big;       // 32 KiB
    R2 r2;                                                   //  8 KiB
};

__launch_bounds__(512, 8)
__global__ void nerf_mfma_kernel(
    const float* __restrict__ g_near, const float* __restrict__ g_far,
    const float* __restrict__ g_center, const float* __restrict__ g_dir,
    const float* __restrict__ W1, const float* __restrict__ b1,
    const float* __restrict__ b2,
    const float* __restrict__ W3, const float* __restrict__ b3,
    const unsigned short* __restrict__ w2h, const unsigned short* __restrict__ w2l,
    float* __restrict__ out, int B)
{
    __shared__ __align__(16) SM sm;

    const int t    = threadIdx.x;
    const int lane = t & 63;
    const int wv   = __builtin_amdgcn_readfirstlane(t >> 6);   // 0..7
    const int r    = blockIdx.x;                               // ray id

    // ---- ray params (block-uniform scalar loads) ----
    const float nr = g_near[r], fa = g_far[r];
    const float cx = g_center[r*3+0], cy = g_center[r*3+1], cz = g_center[r*3+2];
    const float dx = g_dir[r*3+0],    dy = g_dir[r*3+1],    dz = g_dir[r*3+2];

    // ---- phase 1: layer 1 (f32, points recomputed in-register);
    //      h1 -> bf16 A-frags (hi; +lo for mt==3) ----
    {
        const int kbase = wv * 32 + (lane >> 4) * 8;   // 8 consecutive k
        float w1r[3][8], b1r[8];
        #pragma unroll
        for (int c = 0; c < 3; ++c) {
            const f32x4 a = *(const f32x4*)&W1[c * H + kbase];
            const f32x4 b = *(const f32x4*)&W1[c * H + kbase + 4];
            #pragma unroll
            for (int e = 0; e < 4; ++e) { w1r[c][e] = a[e]; w1r[c][e+4] = b[e]; }
        }
        {
            const f32x4 a = *(const f32x4*)&b1[kbase];
            const f32x4 b = *(const f32x4*)&b1[kbase + 4];
            #pragma unroll
            for (int e = 0; e < 4; ++e) { b1r[e] = a[e]; b1r[e+4] = b[e]; }
        }
        const int prow = lane & 15;
        #pragma unroll
        for (int mt = 0; mt < 4; ++mt) {
            const int srow = mt * 16 + prow;
            const float uu = (float)srow * (1.0f / 63.0f);
            const float z  = nr * (1.0f - uu) + fa * uu;
            const float px = cx + z * dx, py = cy + z * dy, pz = cz + z * dz;
            float xs[8];
            #pragma unroll
            for (int e = 0; e < 8; ++e) {
                float x = fmaf(px, w1r[0][e],
                          fmaf(py, w1r[1][e],
                          fmaf(pz, w1r[2][e], b1r[e])));
                xs[e] = fmaxf(x, 0.0f);
            }
            unsigned int hw[4];
            #pragma unroll
            for (int p2 = 0; p2 < 4; ++p2) hw[p2] = pack2bf(xs[p2*2], xs[p2*2+1]);
            *(unsigned int*)&sm.big.ah[((wv*4+mt)*64+lane)*8 + 0] = hw[0];
            *(unsigned int*)&sm.big.ah[((wv*4+mt)*64+lane)*8 + 2] = hw[1];
            *(unsigned int*)&sm.big.ah[((wv*4+mt)*64+lane)*8 + 4] = hw[2];
            *(unsigned int*)&sm.big.ah[((wv*4+mt)*64+lane)*8 + 6] = hw[3];
            if (mt == 3) {
                unsigned int lw[4];
                #pragma unroll
                for (int p2 = 0; p2 < 4; ++p2) {
                    const float l0 = xs[p2*2]   - bf2f((unsigned short)(hw[p2] & 0xffffu));
                    const float l1 = xs[p2*2+1] - bf2f((unsigned short)(hw[p2] >> 16));
                    lw[p2] = pack2bf(l0, l1);
                }
                *(unsigned int*)&sm.r2.a.al3[(wv*64+lane)*8 + 0] = lw[0];
                *(unsigned int*)&sm.r2.a.al3[(wv*64+lane)*8 + 2] = lw[1];
                *(unsigned int*)&sm.r2.a.al3[(wv*64+lane)*8 + 4] = lw[2];
                *(unsigned int*)&sm.r2.a.al3[(wv*64+lane)*8 + 6] = lw[3];
            }
        }
    }
    __syncthreads();

    // ---- phase 2: layer 2 GEMM via MFMA (1-term; mt3 = 3-term) ----
    f32x4 acc[4][2];
    #pragma unroll
    for (int mt = 0; mt < 4; ++mt) {
        acc[mt][0] = (f32x4){0.f,0.f,0.f,0.f};
        acc[mt][1] = (f32x4){0.f,0.f,0.f,0.f};
    }
    {
        const int ntg0 = wv * 2, ntg1 = ntg0 + 1;
        const short8* Bh = (const short8*)w2h;
        const short8* Bl = (const short8*)w2l;
        const short8* Ah = (const short8*)sm.big.ah;
        const short8* Al = (const short8*)sm.r2.a.al3;
        __builtin_amdgcn_s_setprio(1);
        #pragma unroll
        for (int ks = 0; ks < 8; ++ks) {
            const short8 b0h  = Bh[(ks * 16 + ntg0) * 64 + lane];
            const short8 b1h_ = Bh[(ks * 16 + ntg1) * 64 + lane];
            #pragma unroll
            for (int mt = 0; mt < 4; ++mt) {
                const short8 ah = Ah[(ks * 4 + mt) * 64 + lane];
                f32x4 c0 = acc[mt][0], c1 = acc[mt][1];
                c0 = mfma16(ah, b0h, c0);
                c1 = mfma16(ah, b1h_, c1);
                if (mt == 3) {               // sigma-critical rows: full 3-term
                    const short8 b0l = Bl[(ks * 16 + ntg0) * 64 + lane];
                    const short8 b1l = Bl[(ks * 16 + ntg1) * 64 + lane];
                    const short8 al  = Al[ks * 64 + lane];
                    c0 = mfma16(ah, b0l, c0);
                    c0 = mfma16(al, b0h, c0);
                    c1 = mfma16(ah, b1l, c1);
                    c1 = mfma16(al, b1h_, c1);
                }
                acc[mt][0] = c0; acc[mt][1] = c1;
            }
        }
        __builtin_amdgcn_s_setprio(0);
    }
    __syncthreads();   // ah/al3 dead; big->h2f, r2->comb reuse is now safe

    // ---- phase 3: +b2, ReLU; h2 -> A-frag order, k-map g(hi,e)=(e&1)*16+hi*4+(e>>1)
    //      (col pair (j0, j0+16) packs into one u32). NO barrier after: the h2f
    //      region written here is wave-private and re-read only by this wave. ----
    const int  j0 = lane & 15;
    const int  c0 = wv * 32 + j0;
    const int  c1 = c0 + 16;
    const bool lastGrp = ((lane >> 4) == 3);
    float r63a = 0.f, r63b = 0.f;      // f32 h2[63][c0], h2[63][c1] (lastGrp lanes)
    {
        const float b2c0 = b2[c0], b2c1 = b2[c1];
        const int rlow = (lane >> 4) * 4;
        const int hi2  = j0 >> 2;
        const int e0   = (j0 & 3) * 2;
        #pragma unroll
        for (int mt = 0; mt < 4; ++mt) {
            const f32x4 v0 = acc[mt][0], v1 = acc[mt][1];
            #pragma unroll
            for (int q = 0; q < 4; ++q) {
                const float a0 = fmaxf(v0[q] + b2c0, 0.0f);
                const float a1 = fmaxf(v1[q] + b2c1, 0.0f);
                const int l2 = (hi2 << 4) | (rlow + q);
                *(unsigned int*)&sm.big.h2f[((wv*4+mt)*64 + l2)*8 + e0] = pack2bf(a0, a1);
                if (mt == 3 && q == 3) { r63a = a0; r63b = a1; }
            }
        }
    }
    // (no __syncthreads here)

    // ---- phase 4: layer 3 via MFMA, K-split across waves -> comb[wv];
    //      then same-wave DS-ordered overwrite of comb[wv][63][3] with f32 sigma63
    {
        // W3 B-frag with the SAME k-map: k = wv*32 + (e&1)*16 + hi*4 + (e>>1)
        const int n  = lane & 15;
        const int hi = lane >> 4;
        short8 bw3;
        #pragma unroll
        for (int e = 0; e < 8; ++e) {
            const int k = wv * 32 + (e & 1) * 16 + hi * 4 + (e >> 1);
            const float v = (n < 4) ? W3[k * 4 + n] : 0.0f;
            bw3[e] = (short)f2bf(v);
        }
        const short8* Ah2 = (const short8*)sm.big.h2f;
        #pragma unroll
        for (int mt = 0; mt < 4; ++mt) {
            const short8 a = Ah2[(wv * 4 + mt) * 64 + lane];
            f32x4 d = (f32x4){0.f,0.f,0.f,0.f};
            d = mfma16(a, bw3, d);
            if (n < 4) {
                #pragma unroll
                for (int q = 0; q < 4; ++q)
                    sm.r2.b.comb[wv][mt * 16 + hi * 4 + q][n] = d[q];
            }
        }
        if (lastGrp) {   // lanes 48-63 hold row 63; program order => this wins
            float p = fmaf(r63a, W3[c0 * 4 + 3], r63b * W3[c1 * 4 + 3]);
            #pragma unroll
            for (int off = 1; off < 16; off <<= 1) p += __shfl_xor(p, off, 64);
            if (j0 == 0) sm.r2.b.comb[wv][63][3] = p;
        }
    }
    __syncthreads();

    // ---- phase 5: volume rendering (wave 0, lane = sample) ----
    if (t < KS) {
        const int s = t;

        f32x4 oo = (f32x4){0.f,0.f,0.f,0.f};
        #pragma unroll
        for (int q = 0; q < 8; ++q) {
            const f32x4 c = *(const f32x4*)&sm.r2.b.comb[q][s][0];
            oo[0] += c[0]; oo[1] += c[1]; oo[2] += c[2]; oo[3] += c[3];
        }
        const float o0 = oo[0] + b3[0];
        const float o1 = oo[1] + b3[1];
        const float o2 = oo[2] + b3[2];
        const float sigma = oo[3] + b3[3];   // s=63: f32-exact via comb[*][63][3]

        const float uu = (float)s * (1.0f / 63.0f);
        const float z  = nr * (1.0f - uu) + fa * uu;
        const float u2 = (float)(s + 1) * (1.0f / 63.0f);
        const float z2 = nr * (1.0f - u2) + fa * u2;
        const float delta = (s == 63) ? 1e10f : (z2 - z);
        const float alpha = 1.0f - __expf(-delta * fmaxf(sigma, 0.0f));

        // exclusive product scan of (1 - alpha + eps)
        float P = 1.0f - alpha + 1e-8f;
        #pragma unroll
        for (int off = 1; off < 64; off <<= 1) {
            const float v = __shfl_up(P, off, 64);
            if (s >= off) P *= v;
        }
        float T = __shfl_up(P, 1, 64);
        if (s == 0) T = 1.0f;
        const float w = alpha * T;

        out[(size_t)B * 4 + (size_t)r * 64 + s] = w;

        float ws = w, dep = w * z, q0 = w * o0, q1 = w * o1, q2 = w * o2;
        #pragma unroll
        for (int off = 32; off > 0; off >>= 1) {
            ws  += __shfl_xor(ws,  off, 64);
            dep += __shfl_xor(dep, off, 64);
            q0  += __shfl_xor(q0,  off, 64);
            q1  += __shfl_xor(q1,  off, 64);
            q2  += __shfl_xor(q2,  off, 64);
        }
        const float sl = __shfl(sigma, 63, 64);
        if (s == 0) {
            out[(size_t)r * 3 + 0] = q0 + 1.0f - ws;
            out[(size_t)r * 3 + 1] = q1 + 1.0f - ws;
            out[(size_t)r * 3 + 2] = q2 + 1.0f - ws;
            out[(size_t)B * 3 + r] = dep;
            out[(size_t)B * 68 + r] = sl;
        }
    }
}

extern "C" void kernel_launch(void* const* d_in, const int* in_sizes, int n_in,
                              void* d_out, int out_size, void* d_ws, size_t ws_size,
                              hipStream_t stream)
{
    const int B = in_sizes[0];
    if (ws_size < (size_t)(2 * 65536 * sizeof(unsigned short))) return;  // need 256 KiB

    unsigned short* w2h = (unsigned short*)d_ws;
    unsigned short* w2l = w2h + 65536;

    pack_w2_kernel<<<256, 256, 0, stream>>>((const float*)d_in[6], w2h, w2l);

    nerf_mfma_kernel<<<B, 512, 0, stream>>>(
        (const float*)d_in[0], (const float*)d_in[1],
        (const float*)d_in[2], (const float*)d_in[3],
        (const float*)d_in[4], (const float*)d_in[5],
        (const float*)d_in[7],
        (const float*)d_in[8], (const float*)d_in[9],
        w2h, w2l,
        (float*)d_out, B);
}